// Round 13
// baseline (1197.198 us; speedup 1.0000x reference)
//
#include <hip/hip_runtime.h>
#include <hip/hip_bf16.h>

// Problem: x[T=8,B=256,D=4096] fp32; W[D,D] fp32 (row o, col i); b[D] fp32.
// mm[t,b,o] = sum_i x[t,b,i]*W[o,i] + b[o]
// m_t = mm_t + m_{t-1}*(1-s_{t-1})*0.5 ; s_t = (m_t >= 1.0)
// Outputs m,s each [T,B,D], fp32, concatenated in d_out.
//
// Precision: hard threshold -> fp64 accumulation mandatory (R3/R5/R6/R10 verified).
// R10: float-in-LDS f64-MFMA GEMM, 1195us, MfmaUtil 80%, but staging writes
// were 4-way bank-conflicted (stride 72 = 8 mod 32 puts sk*8 = 0 mod 32).
// R11: natural [m][k] tile layout, stride 20 floats:
//   - reads (20*l16+kk) mod 32: 2-way uniform, quarter-waves in disjoint
//     cosets -> free;
//   - staging writes become ONE aligned float4 per array (was 8 scalar
//     scatter stores), uniform bank spans;
//   - LDS 20480 B -> exactly 8 blocks/CU.

#define T_DIM 8
#define B_DIM 256
#define D_DIM 4096
#define M_DIM (T_DIM * B_DIM)   // 2048 GEMM rows

#define BM 64
#define BN 64
#define BK 16
#define NT (D_DIM / BK)          // 256 K-tiles
#define LDSK 20                  // [m][k] row stride in floats

typedef double double4_t __attribute__((ext_vector_type(4)));

// ---- probe: learn the C/D lane->(row,col) map of v_mfma_f64_16x16x4f64 ----
__global__ __launch_bounds__(64) void mfma_probe_kernel(int* __restrict__ map)
{
    const int l = threadIdx.x;
    const int l16 = l & 15;
    const int g = l >> 4;           // k index under assumed A/B layout

    // A[m][k] = m (all k), B[n][k] = delta(k==0)  => D[m][n] = m
    const double am = (double)l16;
    const double bd = (g == 0) ? 1.0 : 0.0;
    // A[m][k] = delta(k==0), B[n][k] = n (all k)  => D[m][n] = n
    const double ad = (g == 0) ? 1.0 : 0.0;
    const double bn = (double)l16;

    double4_t z = {0.0, 0.0, 0.0, 0.0};
    double4_t dm = __builtin_amdgcn_mfma_f64_16x16x4f64(am, bd, z, 0, 0, 0);
    double4_t dn = __builtin_amdgcn_mfma_f64_16x16x4f64(ad, bn, z, 0, 0, 0);

    #pragma unroll
    for (int r = 0; r < 4; ++r) {
        map[l * 8 + r]     = ((int)dm[r]) & 15;  // row of slot (l, r)
        map[l * 8 + 4 + r] = ((int)dn[r]) & 15;  // col of slot (l, r)
    }
}

// ---- fp64 MFMA GEMM: 64x64 tile, 4 waves x (2x2 16x16 frags), BK=16 ----
__global__ __launch_bounds__(256, 8) void gemm_f64_mfma_kernel(
    const float* __restrict__ X,    // [M_DIM][D_DIM]
    const float* __restrict__ W,    // [D_DIM][D_DIM] row-major [o][i]
    const float* __restrict__ bias, // [D_DIM]
    const int* __restrict__ map,    // probed C/D map (in d_out)
    double* __restrict__ MM)        // [M_DIM][D_DIM] fp64 scratch (64 MiB)
{
    // natural [m][k] float tiles, double-buffered; convert to f64 at read
    __shared__ __align__(16) float As[2][BM][LDSK];
    __shared__ __align__(16) float Bs[2][BN][LDSK];

    const int tid = threadIdx.x;
    const int bm = blockIdx.y * BM;
    const int bn = blockIdx.x * BN;

    // staging: thread -> (row sr, k-quad sk); one float4 of X and of W per tile
    const int sr = tid >> 2;          // 0..63
    const int sk = (tid & 3) << 2;    // 0,4,8,12

    // 4 waves, each owns a 32x32 quadrant (2x2 MFMA 16x16 blocks)
    const int wave = tid >> 6;
    const int wr = (wave >> 1) << 5;  // 0 or 32
    const int wc = (wave & 1) << 5;   // 0 or 32
    const int lane = tid & 63;
    const int l16 = lane & 15;
    const int g = lane >> 4;

    double4_t acc00 = {0,0,0,0}, acc01 = {0,0,0,0};
    double4_t acc10 = {0,0,0,0}, acc11 = {0,0,0,0};

    const float* xp = X + (size_t)(bm + sr) * D_DIM + sk;
    const float* wp = W + (size_t)(bn + sr) * D_DIM + sk;

    // prologue: stage tile 0 into buffer 0 (single aligned float4 per array)
    {
        const float4 av = *reinterpret_cast<const float4*>(xp);
        const float4 bv = *reinterpret_cast<const float4*>(wp);
        *reinterpret_cast<float4*>(&As[0][sr][sk]) = av;
        *reinterpret_cast<float4*>(&Bs[0][sr][sk]) = bv;
    }
    __syncthreads();

    for (int t = 0; t < NT; ++t) {
        const int cur = t & 1;

        // issue next-tile global loads early (hide HBM/L2 latency under MFMA)
        float4 av, bv;
        if (t < NT - 1) {
            const int k0 = (t + 1) * BK;
            av = *reinterpret_cast<const float4*>(xp + k0);
            bv = *reinterpret_cast<const float4*>(wp + k0);
        }

        // compute current tile: 16 MFMAs (4 per K=4 step)
        #pragma unroll
        for (int s = 0; s < 4; ++s) {
            const int kk = 4 * s + g;
            const double a0 = (double)As[cur][wr + l16][kk];
            const double a1 = (double)As[cur][wr + 16 + l16][kk];
            const double b0 = (double)Bs[cur][wc + l16][kk];
            const double b1 = (double)Bs[cur][wc + 16 + l16][kk];
            acc00 = __builtin_amdgcn_mfma_f64_16x16x4f64(a0, b0, acc00, 0, 0, 0);
            acc01 = __builtin_amdgcn_mfma_f64_16x16x4f64(a0, b1, acc01, 0, 0, 0);
            acc10 = __builtin_amdgcn_mfma_f64_16x16x4f64(a1, b0, acc10, 0, 0, 0);
            acc11 = __builtin_amdgcn_mfma_f64_16x16x4f64(a1, b1, acc11, 0, 0, 0);
        }

        // stage next tile into the other buffer
        if (t < NT - 1) {
            const int nxt = cur ^ 1;
            *reinterpret_cast<float4*>(&As[nxt][sr][sk]) = av;
            *reinterpret_cast<float4*>(&Bs[nxt][sr][sk]) = bv;
        }
        __syncthreads();
    }

    // epilogue through the probed map: slot (lane, r) -> (row, col)
    int mrow[4], mcol[4];
    #pragma unroll
    for (int r = 0; r < 4; ++r) {
        mrow[r] = map[lane * 8 + r];
        mcol[r] = map[lane * 8 + 4 + r];
    }

    const double4_t* accs[4] = {&acc00, &acc01, &acc10, &acc11};
    #pragma unroll
    for (int mb = 0; mb < 2; ++mb) {
        #pragma unroll
        for (int nb = 0; nb < 2; ++nb) {
            const double4_t a = *accs[mb * 2 + nb];
            #pragma unroll
            for (int r = 0; r < 4; ++r) {
                const int row = bm + wr + mb * 16 + mrow[r];
                const int col = bn + wc + nb * 16 + mcol[r];
                MM[(size_t)row * D_DIM + col] = a[r] + (double)bias[col];
            }
        }
    }
}

__global__ __launch_bounds__(256) void recur_kernel(
    const double* __restrict__ MM,
    float* __restrict__ out)   // fp32 outputs: m then s, each [T,B,D]
{
    const size_t stride = (size_t)B_DIM * D_DIM;  // 1,048,576
    const size_t idx = (size_t)blockIdx.x * 256 + threadIdx.x;

    float* out_m = out;
    float* out_s = out + (size_t)T_DIM * stride;

    double m_prev = 0.0;
    double s_prev = 0.0;
    #pragma unroll
    for (int t = 0; t < T_DIM; ++t) {
        const double mm = MM[(size_t)t * stride + idx];
        const double m = mm + m_prev * (1.0 - s_prev) * 0.5;
        const double s = (m >= 1.0) ? 1.0 : 0.0;
        out_m[(size_t)t * stride + idx] = (float)m;
        out_s[(size_t)t * stride + idx] = (float)s;
        m_prev = m;
        s_prev = s;
    }
}

extern "C" void kernel_launch(void* const* d_in, const int* in_sizes, int n_in,
                              void* d_out, int out_size, void* d_ws, size_t ws_size,
                              hipStream_t stream) {
    // Identify inputs by element count (dict order is x, W, b).
    const float* x = (const float*)d_in[0];
    const float* W = (const float*)d_in[1];
    const float* b = (const float*)d_in[2];
    for (int i = 0; i < n_in; ++i) {
        if (in_sizes[i] == D_DIM) b = (const float*)d_in[i];
        else if (in_sizes[i] == D_DIM * D_DIM) W = (const float*)d_in[i];
        else if (in_sizes[i] == M_DIM * D_DIM) x = (const float*)d_in[i];
    }

    double* MM = (double*)d_ws;        // M_DIM*D_DIM*8 = 64 MiB
    int* map = (int*)d_out;            // 512 ints; recur_kernel overwrites all
                                       // of d_out afterwards (stream-ordered)

    mfma_probe_kernel<<<1, 64, 0, stream>>>(map);

    dim3 grid_gemm(D_DIM / BN, M_DIM / BM);  // (64, 32) = 2048 blocks
    gemm_f64_mfma_kernel<<<grid_gemm, 256, 0, stream>>>(x, W, b, map, MM);

    const int n_bd = B_DIM * D_DIM;  // 1,048,576
    recur_kernel<<<n_bd / 256, 256, 0, stream>>>(MM, (float*)d_out);
}